// Round 3
// baseline (200.050 us; speedup 1.0000x reference)
//
#include <hip/hip_runtime.h>
#include <math.h>

#define BB 8
#define CC 32
#define NTOK 241   // 4(q 2x2) + 121 + 64 + 36 + 16
#define NKV 237
#define QSPLIT 4   // blocks per plane (row quarters)
#define RB 128     // rows per block
#define NSLOT 10   // max LDS Y rows/block: p2:1 p11:4 p8:2 p6:2 p4:1
#define YPADW 516

// ---------------------------------------------------------------------------
// Kernel A (v3): H-first adaptive pooling, 4 blocks per plane for full
// occupancy (1024 blocks, 32 waves/CU). Thread = column, walks 128 rows with
// per-level window machines; complete windows -> plain token stores, windows
// straddling a quarter boundary -> scaled atomicAdd (2 contributors, exact).
// ---------------------------------------------------------------------------
struct Lvl { int i; int eh; float acc; };

template <int P>
__device__ __forceinline__ void lvl_init(Lvl& st, int lo, int hi) {
  st.i = (lo * P) >> 9;                      // first window with e(i) > lo
  int e = ((st.i + 1) * 512 + P - 1) / P;
  st.eh = min(e, hi);
  st.acc = 0.0f;
}

template <int P, int BASE>
__device__ __forceinline__ void lvl_step(Lvl& st, float v, int r, int hi,
                                         float* Y, int c, int& slot) {
  st.acc += v;
  if (r == st.eh - 1) {                      // block-uniform branch
    Y[(BASE + slot) * YPADW + c] = st.acc;   // raw sum
    slot++;
    st.i++;
    int sn = (st.i * 512) / P;
    int e = ((st.i + 1) * 512 + P - 1) / P;
    st.eh = min(e, hi);
    st.acc = (sn <= r) ? v : 0.0f;           // adjacent windows overlap <=1 row
  }
}

template <int P, int BASE>
__device__ __forceinline__ void lvl_fin(Lvl& st, int hi, float* Y, int c,
                                        int& slot) {
  int sn = (st.i * 512) / P;                 // trailing 1-row window start
  if (sn < hi) { Y[(BASE + slot) * YPADW + c] = st.acc; slot++; }
}

__global__ __launch_bounds__(512) void pool_kernel(const float* __restrict__ x,
                                                   float* __restrict__ pooled) {
  __shared__ float Ybuf[NSLOT * YPADW];      // 20,640 B

  const int plane = blockIdx.x >> 2;         // b*32 + c
  const int q = blockIdx.x & 3;
  const int lo = q * RB, hi = lo + RB;
  const int c = threadIdx.x;                 // column 0..511
  const float* xp = x + (size_t)plane * (512 * 512) + c;

  Lvl L2v, L11, L8, L6, L4;
  lvl_init<2>(L2v, lo, hi);
  lvl_init<11>(L11, lo, hi);
  lvl_init<8>(L8, lo, hi);
  lvl_init<6>(L6, lo, hi);
  lvl_init<4>(L4, lo, hi);
  int s2 = 0, s11 = 0, s8 = 0, s6 = 0, s4 = 0;

  float A[8], B[8];
#pragma unroll
  for (int u = 0; u < 8; ++u) A[u] = xp[(size_t)(lo + u) * 512];

  for (int cb = 0; cb < RB; cb += 16) {
#pragma unroll
    for (int u = 0; u < 8; ++u) B[u] = xp[(size_t)(lo + cb + 8 + u) * 512];
#pragma unroll
    for (int u = 0; u < 8; ++u) {
      float v = A[u]; int r = lo + cb + u;
      lvl_step<2, 0>(L2v, v, r, hi, Ybuf, c, s2);
      lvl_step<11, 1>(L11, v, r, hi, Ybuf, c, s11);
      lvl_step<8, 5>(L8, v, r, hi, Ybuf, c, s8);
      lvl_step<6, 7>(L6, v, r, hi, Ybuf, c, s6);
      lvl_step<4, 9>(L4, v, r, hi, Ybuf, c, s4);
    }
    if (cb + 16 < RB) {
#pragma unroll
      for (int u = 0; u < 8; ++u) A[u] = xp[(size_t)(lo + cb + 16 + u) * 512];
    }
#pragma unroll
    for (int u = 0; u < 8; ++u) {
      float v = B[u]; int r = lo + cb + 8 + u;
      lvl_step<2, 0>(L2v, v, r, hi, Ybuf, c, s2);
      lvl_step<11, 1>(L11, v, r, hi, Ybuf, c, s11);
      lvl_step<8, 5>(L8, v, r, hi, Ybuf, c, s8);
      lvl_step<6, 7>(L6, v, r, hi, Ybuf, c, s6);
      lvl_step<4, 9>(L4, v, r, hi, Ybuf, c, s4);
    }
  }
  lvl_fin<2, 0>(L2v, hi, Ybuf, c, s2);
  lvl_fin<11, 1>(L11, hi, Ybuf, c, s11);
  lvl_fin<8, 5>(L8, hi, Ybuf, c, s8);
  lvl_fin<6, 7>(L6, hi, Ybuf, c, s6);
  lvl_fin<4, 9>(L4, hi, Ybuf, c, s4);
  __syncthreads();

  // Phase 2: W-pool each Y slot row into tokens.
  const int Ps[5]  = {2, 11, 8, 6, 4};
  const int KBs[5] = {0, 4, 125, 189, 225};
  const int BSs[5] = {0, 1, 5, 7, 9};
  int ifir[5], cum[6]; cum[0] = 0;
#pragma unroll
  for (int l = 0; l < 5; ++l) {
    int P = Ps[l];
    ifir[l] = (lo * P) >> 9;
    int iend = (hi * P + 511) >> 9;          // first window with s >= hi
    cum[l + 1] = cum[l] + (iend - ifir[l]) * P;
  }
  if (c < cum[5]) {
    int l = 0;
    while (c >= cum[l + 1]) ++l;
    int P = Ps[l];
    int rel = c - cum[l];
    int slot = rel / P, j = rel - slot * P;
    int i = ifir[l] + slot;
    int si = (i * 512) / P, ei = ((i + 1) * 512 + P - 1) / P;
    int sw = (j * 512) / P, ew = ((j + 1) * 512 + P - 1) / P;
    const float* row = &Ybuf[(BSs[l] + slot) * YPADW];
    float t0 = 0.f, t1 = 0.f, t2 = 0.f, t3 = 0.f;
    int cc = sw;
    for (; cc + 4 <= ew; cc += 4) {
      t0 += row[cc]; t1 += row[cc + 1]; t2 += row[cc + 2]; t3 += row[cc + 3];
    }
    for (; cc < ew; ++cc) t0 += row[cc];
    float val = ((t0 + t1) + (t2 + t3)) / (float)((ei - si) * (ew - sw));
    int idx = plane * NTOK + KBs[l] + i * P + j;
    if (si >= lo && ei <= hi) pooled[idx] = val;       // sole owner
    else atomicAdd(&pooled[idx], val);                 // exactly 2 contributors
  }
}

// ---------------------------------------------------------------------------
// Kernel B: token pipeline (dw-conv residual, LN, q/kv linears, attention,
// proj). One block per batch element.
// ---------------------------------------------------------------------------
__global__ __launch_bounds__(512) void attn_kernel(
    const float* __restrict__ pooled,
    const float* __restrict__ q_w, const float* __restrict__ q_b,
    const float* __restrict__ kv_w, const float* __restrict__ kv_b,
    const float* __restrict__ proj_w, const float* __restrict__ proj_b,
    const float* __restrict__ norm_g, const float* __restrict__ norm_b,
    const float* __restrict__ dconv_w, const float* __restrict__ dconv_b,
    float* __restrict__ o_out) {
  __shared__ float pl[CC * NTOK];
  __shared__ float toks[NKV][33];
  __shared__ float kvls[NKV][65];      // k: 0..31, v: 32..63
  __shared__ float kvw[CC * 64];
  __shared__ float dw[4 * CC * 9];
  __shared__ float dbias[4 * CC];
  __shared__ float qbias[CC], kvb[64], gln[CC], bln[CC];
  __shared__ float qtok[4][CC];
  __shared__ float attno[4][33];

  const int b = blockIdx.x, tid = threadIdx.x;
  const float* plg = pooled + (size_t)b * CC * NTOK;
  for (int i = tid; i < CC * NTOK; i += 512) pl[i] = plg[i];
  for (int i = tid; i < CC * 64; i += 512) kvw[i] = kv_w[i];
  for (int i = tid; i < 4 * CC * 9; i += 512) dw[i] = dconv_w[i];
  if (tid < 4 * CC) dbias[tid] = dconv_b[tid];
  if (tid < CC) { qbias[tid] = q_b[tid]; gln[tid] = norm_g[tid]; bln[tid] = norm_b[tid]; }
  if (tid >= 64 && tid < 128) kvb[tid - 64] = kv_b[tid - 64];
  __syncthreads();

  // depthwise 3x3 conv (SAME, zero pad) + residual -> toks
  for (int item = tid; item < NKV * CC; item += 512) {
    int t = item >> 5, c = item & 31;
    int l, p, kb_, tb;
    if (t < 121)      { l = 0; p = 11; kb_ = 4;   tb = 0; }
    else if (t < 185) { l = 1; p = 8;  kb_ = 125; tb = 121; }
    else if (t < 221) { l = 2; p = 6;  kb_ = 189; tb = 185; }
    else              { l = 3; p = 4;  kb_ = 225; tb = 221; }
    int ti = t - tb;
    int i = ti / p, j = ti - i * p;
    const float* plc = pl + c * NTOK + kb_;
    const float* w9 = dw + (l * CC + c) * 9;
    float acc = dbias[l * CC + c];
#pragma unroll
    for (int dy = -1; dy <= 1; ++dy)
#pragma unroll
      for (int dx = -1; dx <= 1; ++dx) {
        int ii = i + dy, jj = j + dx;
        if (ii >= 0 && ii < p && jj >= 0 && jj < p)
          acc += w9[(dy + 1) * 3 + (dx + 1)] * plc[ii * p + jj];
      }
    toks[t][c] = plc[i * p + j] + acc;
  }
  __syncthreads();

  // LayerNorm over C (threads 0..236) ; q linear (threads 384..511)
  if (tid < NKV) {
    float xv[32]; float m = 0.f;
#pragma unroll
    for (int c = 0; c < 32; ++c) { xv[c] = toks[tid][c]; m += xv[c]; }
    m *= (1.0f / 32.0f);
    float v = 0.f;
#pragma unroll
    for (int c = 0; c < 32; ++c) { float d = xv[c] - m; v += d * d; }
    v *= (1.0f / 32.0f);
    float rs = rsqrtf(v + 1e-5f);
#pragma unroll
    for (int c = 0; c < 32; ++c) toks[tid][c] = (xv[c] - m) * rs * gln[c] + bln[c];
  } else if (tid >= 384) {
    int it = tid - 384;
    int n = it >> 5, u = it & 31;
    float acc = qbias[u];
#pragma unroll
    for (int c = 0; c < 32; ++c) acc += pl[c * NTOK + n] * q_w[c * 32 + u];
    qtok[n][u] = acc * 0.25f;         // fold scale = hd^-0.5
  }
  __syncthreads();

  // kv = toks_ln @ kv_w + kv_b   (237 x 64)
  for (int item = tid; item < NKV * 64; item += 512) {
    int t = item >> 6, u = item & 63;
    float acc = kvb[u];
#pragma unroll
    for (int c = 0; c < 32; ++c) acc += toks[t][c] * kvw[c * 64 + u];
    kvls[t][u] = acc;
  }
  __syncthreads();

  // attention: 8 waves <-> 8 (head, query) pairs
  {
    int wave = tid >> 6, lane = tid & 63;
    int h = wave >> 2, qi = wave & 3;
    float qv[16];
#pragma unroll
    for (int d = 0; d < 16; ++d) qv[d] = qtok[qi][h * 16 + d];
    float sc[4];
#pragma unroll
    for (int m = 0; m < 4; ++m) {
      int t = lane + m * 64;
      float s = -1e30f;
      if (t < NKV) {
        s = 0.f;
#pragma unroll
        for (int d = 0; d < 16; ++d) s += qv[d] * kvls[t][h * 16 + d];
      }
      sc[m] = s;
    }
    float mx = fmaxf(fmaxf(sc[0], sc[1]), fmaxf(sc[2], sc[3]));
#pragma unroll
    for (int d = 1; d < 64; d <<= 1) mx = fmaxf(mx, __shfl_xor(mx, d));
    float pr[4]; float ssum = 0.f;
#pragma unroll
    for (int m = 0; m < 4; ++m) {
      int t = lane + m * 64;
      pr[m] = (t < NKV) ? expf(sc[m] - mx) : 0.0f;
      ssum += pr[m];
    }
#pragma unroll
    for (int d = 1; d < 64; d <<= 1) ssum += __shfl_xor(ssum, d);
    float acc[16];
#pragma unroll
    for (int d = 0; d < 16; ++d) acc[d] = 0.f;
#pragma unroll
    for (int m = 0; m < 4; ++m) {
      int t = lane + m * 64;
      if (t < NKV) {
        float p = pr[m];
#pragma unroll
        for (int d = 0; d < 16; ++d) acc[d] += p * kvls[t][32 + h * 16 + d];
      }
    }
#pragma unroll
    for (int d = 0; d < 16; ++d) {
#pragma unroll
      for (int s = 1; s < 64; s <<= 1) acc[d] += __shfl_xor(acc[d], s);
    }
    if (lane == 0) {
      float inv = 1.0f / ssum;
#pragma unroll
      for (int d = 0; d < 16; ++d) attno[qi][h * 16 + d] = acc[d] * inv;
    }
  }
  __syncthreads();

  // proj: (4 x 32) @ proj_w + proj_b -> o_out[(b*32+u)*4 + n]
  if (tid < 128) {
    int n = tid >> 5, u = tid & 31;
    float acc = proj_b[u];
#pragma unroll
    for (int c = 0; c < 32; ++c) acc += attno[n][c] * proj_w[c * 32 + u];
    o_out[((size_t)b * 32 + u) * 4 + n] = acc;
  }
}

// ---------------------------------------------------------------------------
// Kernel C: bilinear upsample 2x2 -> 512x512 (align_corners=False, clamped).
// ---------------------------------------------------------------------------
__global__ __launch_bounds__(256) void upsample_kernel(const float* __restrict__ o_in,
                                                       float* __restrict__ out) {
  const int plane = blockIdx.x >> 3;
  const int chunk = blockIdx.x & 7;
  const int tid = threadIdx.x;
  const int sub = tid >> 7, col4 = tid & 127;

  const float o00 = o_in[plane * 4 + 0];
  const float o01 = o_in[plane * 4 + 1];
  const float o10 = o_in[plane * 4 + 2];
  const float o11 = o_in[plane * 4 + 3];

  float top[4], bot[4];
#pragma unroll
  for (int k = 0; k < 4; ++k) {
    float c = (float)(4 * col4 + k) + 0.5f;
    float ww = c * (1.0f / 256.0f) - 0.5f;
    ww = fminf(fmaxf(ww, 0.0f), 1.0f);
    top[k] = o00 + ww * (o01 - o00);
    bot[k] = o10 + ww * (o11 - o10);
  }
  float* outp = out + (size_t)plane * (512 * 512);
  const int r0 = chunk * 64;
  for (int i = 0; i < 32; ++i) {
    int r = r0 + 2 * i + sub;
    float wh = ((float)r + 0.5f) * (1.0f / 256.0f) - 0.5f;
    wh = fminf(fmaxf(wh, 0.0f), 1.0f);
    float4 v;
    v.x = top[0] + wh * (bot[0] - top[0]);
    v.y = top[1] + wh * (bot[1] - top[1]);
    v.z = top[2] + wh * (bot[2] - top[2]);
    v.w = top[3] + wh * (bot[3] - top[3]);
    *(float4*)(outp + r * 512 + 4 * col4) = v;
  }
}

extern "C" void kernel_launch(void* const* d_in, const int* in_sizes, int n_in,
                              void* d_out, int out_size, void* d_ws, size_t ws_size,
                              hipStream_t stream) {
  const float* x       = (const float*)d_in[0];
  const float* q_w     = (const float*)d_in[1];
  const float* q_b     = (const float*)d_in[2];
  const float* kv_w    = (const float*)d_in[3];
  const float* kv_b    = (const float*)d_in[4];
  const float* proj_w  = (const float*)d_in[5];
  const float* proj_b  = (const float*)d_in[6];
  const float* norm_g  = (const float*)d_in[7];
  const float* norm_b  = (const float*)d_in[8];
  const float* dconv_w = (const float*)d_in[9];
  const float* dconv_b = (const float*)d_in[10];
  float* out = (float*)d_out;

  float* pooled = (float*)d_ws;                     // 256*241 floats
  float* o_ws   = pooled + (size_t)BB * CC * NTOK;  // 1024 floats

  hipMemsetAsync(d_ws, 0, (size_t)BB * CC * NTOK * sizeof(float), stream);
  pool_kernel<<<BB * CC * QSPLIT, 512, 0, stream>>>(x, pooled);
  attn_kernel<<<BB, 512, 0, stream>>>(pooled, q_w, q_b, kv_w, kv_b, proj_w,
                                      proj_b, norm_g, norm_b, dconv_w, dconv_b,
                                      o_ws);
  upsample_kernel<<<BB * CC * 8, 256, 0, stream>>>(o_ws, out);
}